// Round 2
// baseline (1344.232 us; speedup 1.0000x reference)
//
#include <hip/hip_runtime.h>

// Fused 4-layer RNN (LSTM,LSTM,GRU,GRU, H=64) + FC head. B=2048, T=512.
// 256 blocks x 512 threads (8 waves) = 2 waves/SIMD. Gate-split: each wave
// owns 2-3 MFMA N-tiles (gate x h-chunk) -> 24 weight frags/wave (96 VGPR).
// MFMA waves write bias-folded pre-activation gates (f32) to LDS; a uniform
// (row,dim) lane map applies activations; c/h state fp32 in owning lane regs.

#define TT 512

typedef __attribute__((ext_vector_type(8))) short bfrag;  // 8 bf16
typedef __attribute__((ext_vector_type(4))) float facc;   // 4 f32

#define MFMA(a,b,c) __builtin_amdgcn_mfma_f32_16x16x32_bf16((a),(b),(c),0,0,0)

__device__ __forceinline__ short f2bf(float f){
  union { float f; unsigned u; } v; v.f = f;
  return (short)((v.u + 0x7fffu + ((v.u >> 16) & 1u)) >> 16);  // RNE
}
__device__ __forceinline__ float sigm(float xx){
  return __builtin_amdgcn_rcpf(1.0f + __expf(-xx));
}
__device__ __forceinline__ float tanh_(float xx){
  return 2.0f * __builtin_amdgcn_rcpf(1.0f + __expf(-2.0f * xx)) - 1.0f;
}

#define RB0 72    // zL0 row stride (bf16 elems), odd*8 -> 16B rows
#define RB1 136   // dual [x|h] buffers row stride
#define GS  389   // gates row stride (f32); 389%32==5 -> rows spread banks

__global__ __launch_bounds__(512, 2) void rnn_fused(
    const float* __restrict__ x,
    const float* __restrict__ lw_ih0, const float* __restrict__ lw_hh0,
    const float* __restrict__ lb_ih0, const float* __restrict__ lb_hh0,
    const float* __restrict__ lw_ih1, const float* __restrict__ lw_hh1,
    const float* __restrict__ lb_ih1, const float* __restrict__ lb_hh1,
    const float* __restrict__ gw_ih0, const float* __restrict__ gw_hh0,
    const float* __restrict__ gb_ih0, const float* __restrict__ gb_hh0,
    const float* __restrict__ gw_ih1, const float* __restrict__ gw_hh1,
    const float* __restrict__ gb_ih1, const float* __restrict__ gb_hh1,
    const float* __restrict__ fc_w, const float* __restrict__ fc_b,
    float* __restrict__ out)
{
  __shared__ __align__(16) short zL0[16 * RB0];  // h0 state (cols 0-63)
  __shared__ __align__(16) short zL1[16 * RB1];  // [h0_t | h1_prev]
  __shared__ __align__(16) short zG0[16 * RB1];  // [h1_t | hg0_prev]
  __shared__ __align__(16) short zG1[16 * RB1];  // [hg0_t | hg1_prev]
  __shared__ float gates[16 * GS];               // pre-activation gate values
  __shared__ float xs[8][64];
  __shared__ float hfin[16][72];

  const int tid = threadIdx.x;
  const int w   = tid >> 6;      // wave 0..7
  const int l   = tid & 63;
  const int lq  = l >> 4;
  const int lc  = l & 15;
  const int r0  = lq * 4;        // C-layout row base
  const int kb  = lq * 8;        // B/A-frag k-offset
  const int rb0 = blockIdx.x * 8;

  // LSTM N-tiles for this wave: gate gL = w>>1, chunks {2*(w&1), 2*(w&1)+1}
  const int gL   = w >> 1;
  const int colA = gL * 64 + (w & 1) * 32 + lc;
  const int colB = colA + 16;

  // GRU tiles: kind 0 = x-part (waves 0-3), 1 = h-part (waves 4-7); 3 tiles
  const int kind = w >> 2;
  const int gw3  = w & 3;
  int colG[3];
  #pragma unroll
  for (int i = 0; i < 3; ++i) {
    const int tau = 3 * gw3 + i;
    colG[i] = (tau >> 2) * 64 + (tau & 3) * 16 + lc;
  }

  // ---------------- weights -> VGPRs (this wave's tiles only) ----------------
  // B-frag (16x16x32): col = lane&15, k = (lane>>4)*8 + j.
  bfrag wL0[2][2], wL1[2][4], wg0[3][2], wg1[3][2];
  #pragma unroll
  for (int tI = 0; tI < 2; ++tI) {
    const int jw = tI ? colB : colA;
    #pragma unroll
    for (int kt = 0; kt < 2; ++kt) {
      bfrag f;
      #pragma unroll
      for (int j = 0; j < 8; ++j) f[j] = f2bf(lw_hh0[jw * 64 + kt * 32 + kb + j]);
      wL0[tI][kt] = f;
    }
    #pragma unroll
    for (int kt = 0; kt < 4; ++kt) {
      const float* src = (kt < 2) ? lw_ih1 : lw_hh1;
      const int ko = (kt & 1) * 32;
      bfrag f;
      #pragma unroll
      for (int j = 0; j < 8; ++j) f[j] = f2bf(src[jw * 64 + ko + kb + j]);
      wL1[tI][kt] = f;
    }
  }
  {
    const float* s0 = kind ? gw_hh0 : gw_ih0;
    const float* s1 = kind ? gw_hh1 : gw_ih1;
    #pragma unroll
    for (int i = 0; i < 3; ++i) {
      #pragma unroll
      for (int kt = 0; kt < 2; ++kt) {
        bfrag f, g;
        #pragma unroll
        for (int j = 0; j < 8; ++j) {
          f[j] = f2bf(s0[colG[i] * 64 + kt * 32 + kb + j]);
          g[j] = f2bf(s1[colG[i] * 64 + kt * 32 + kb + j]);
        }
        wg0[i][kt] = f; wg1[i][kt] = g;
      }
    }
  }
  // biases folded per tile-col (GRU n-gate: bh stays inside h-part: correct
  // since n = tanh(xn + bxn + r*(hn + bhn)))
  const float bL0A = lb_ih0[colA] + lb_hh0[colA];
  const float bL0B = lb_ih0[colB] + lb_hh0[colB];
  const float wxA  = lw_ih0[colA], wxB = lw_ih0[colB];
  const float bL1A = lb_ih1[colA] + lb_hh1[colA];
  const float bL1B = lb_ih1[colB] + lb_hh1[colB];
  float bg0[3], bg1[3];
  {
    const float* b0 = kind ? gb_hh0 : gb_ih0;
    const float* b1 = kind ? gb_hh1 : gb_ih1;
    #pragma unroll
    for (int i = 0; i < 3; ++i) { bg0[i] = b0[colG[i]]; bg1[i] = b1[colG[i]]; }
  }

  // elementwise lane map: lane (r_e, d_e) owns dims d_e and d_e+32 of row r_e
  const int r_e = tid & 15;
  const int d_e = tid >> 4;   // 0..31
  const int gb  = r_e * GS;

  for (int i = tid; i < 16 * RB0; i += 512) zL0[i] = 0;
  for (int i = tid; i < 16 * RB1; i += 512) { zL1[i] = 0; zG0[i] = 0; zG1[i] = 0; }
  __syncthreads();

  float c0[2] = {0,0}, c1[2] = {0,0}, hg0[2] = {0,0}, hg1[2] = {0,0};

  #pragma unroll 1
  for (int t = 0; t < TT; ++t) {
    if ((t & 63) == 0) {  // stage 64 timesteps of x for our 8 rows
      xs[tid >> 6][tid & 63] = x[(rb0 + (tid >> 6)) * TT + t + (tid & 63)];
      __syncthreads();
    }

    // ===== LSTM0: MFMA phase =====
    {
      const bfrag a0 = *(const bfrag*)(zL0 + lc * RB0 + kb);
      const bfrag a1 = *(const bfrag*)(zL0 + lc * RB0 + 32 + kb);
      facc aA = {0,0,0,0}, aB = {0,0,0,0};
      aA = MFMA(a0, wL0[0][0], aA); aA = MFMA(a1, wL0[0][1], aA);
      aB = MFMA(a0, wL0[1][0], aB); aB = MFMA(a1, wL0[1][1], aB);
      #pragma unroll
      for (int m = 0; m < 4; ++m) {
        const float xv = xs[(r0 + m) & 7][t & 63];
        gates[(r0 + m) * GS + colA] = aA[m] + xv * wxA + bL0A;
        gates[(r0 + m) * GS + colB] = aB[m] + xv * wxB + bL0B;
      }
    }
    __syncthreads();
    // ===== LSTM0: elementwise =====
    #pragma unroll
    for (int q = 0; q < 2; ++q) {
      const int d = d_e + q * 32;
      const float i_ = sigm (gates[gb + d]);
      const float f_ = sigm (gates[gb + 64 + d]);
      const float g_ = tanh_(gates[gb + 128 + d]);
      const float o_ = sigm (gates[gb + 192 + d]);
      c0[q] = f_ * c0[q] + i_ * g_;
      const short hb = f2bf(o_ * tanh_(c0[q]));
      zL0[r_e * RB0 + d] = hb;
      zL1[r_e * RB1 + d] = hb;
    }
    __syncthreads();

    // ===== LSTM1: MFMA phase (K=128: [h0_t | h1_prev]) =====
    {
      const bfrag a0 = *(const bfrag*)(zL1 + lc * RB1 + kb);
      const bfrag a1 = *(const bfrag*)(zL1 + lc * RB1 + 32 + kb);
      const bfrag a2 = *(const bfrag*)(zL1 + lc * RB1 + 64 + kb);
      const bfrag a3 = *(const bfrag*)(zL1 + lc * RB1 + 96 + kb);
      facc aA = {0,0,0,0}, aB = {0,0,0,0};
      aA = MFMA(a0, wL1[0][0], aA); aA = MFMA(a1, wL1[0][1], aA);
      aA = MFMA(a2, wL1[0][2], aA); aA = MFMA(a3, wL1[0][3], aA);
      aB = MFMA(a0, wL1[1][0], aB); aB = MFMA(a1, wL1[1][1], aB);
      aB = MFMA(a2, wL1[1][2], aB); aB = MFMA(a3, wL1[1][3], aB);
      #pragma unroll
      for (int m = 0; m < 4; ++m) {
        gates[(r0 + m) * GS + colA] = aA[m] + bL1A;
        gates[(r0 + m) * GS + colB] = aB[m] + bL1B;
      }
    }
    __syncthreads();
    // ===== LSTM1: elementwise =====
    #pragma unroll
    for (int q = 0; q < 2; ++q) {
      const int d = d_e + q * 32;
      const float i_ = sigm (gates[gb + d]);
      const float f_ = sigm (gates[gb + 64 + d]);
      const float g_ = tanh_(gates[gb + 128 + d]);
      const float o_ = sigm (gates[gb + 192 + d]);
      c1[q] = f_ * c1[q] + i_ * g_;
      const short hb = f2bf(o_ * tanh_(c1[q]));
      zL1[r_e * RB1 + 64 + d] = hb;
      zG0[r_e * RB1 + d] = hb;
    }
    __syncthreads();

    // ===== GRU0: MFMA phase (x-part waves read cols 0-63, h-part 64-127) =====
    {
      const int off = kind * 64;
      const bfrag a0 = *(const bfrag*)(zG0 + lc * RB1 + off + kb);
      const bfrag a1 = *(const bfrag*)(zG0 + lc * RB1 + off + 32 + kb);
      facc ac[3];
      #pragma unroll
      for (int i = 0; i < 3; ++i) {
        facc a_ = {0,0,0,0};
        a_ = MFMA(a0, wg0[i][0], a_);
        a_ = MFMA(a1, wg0[i][1], a_);
        ac[i] = a_;
      }
      #pragma unroll
      for (int i = 0; i < 3; ++i)
        #pragma unroll
        for (int m = 0; m < 4; ++m)
          gates[(r0 + m) * GS + kind * 192 + colG[i]] = ac[i][m] + bg0[i];
    }
    __syncthreads();
    // ===== GRU0: elementwise =====
    #pragma unroll
    for (int q = 0; q < 2; ++q) {
      const int d = d_e + q * 32;
      const float r_ = sigm (gates[gb + d]       + gates[gb + 192 + d]);
      const float z_ = sigm (gates[gb + 64 + d]  + gates[gb + 256 + d]);
      const float n_ = tanh_(gates[gb + 128 + d] + r_ * gates[gb + 320 + d]);
      hg0[q] = (1.0f - z_) * n_ + z_ * hg0[q];
      const short hb = f2bf(hg0[q]);
      zG0[r_e * RB1 + 64 + d] = hb;
      zG1[r_e * RB1 + d] = hb;
    }
    __syncthreads();

    // ===== GRU1: MFMA phase =====
    {
      const int off = kind * 64;
      const bfrag a0 = *(const bfrag*)(zG1 + lc * RB1 + off + kb);
      const bfrag a1 = *(const bfrag*)(zG1 + lc * RB1 + off + 32 + kb);
      facc ac[3];
      #pragma unroll
      for (int i = 0; i < 3; ++i) {
        facc a_ = {0,0,0,0};
        a_ = MFMA(a0, wg1[i][0], a_);
        a_ = MFMA(a1, wg1[i][1], a_);
        ac[i] = a_;
      }
      #pragma unroll
      for (int i = 0; i < 3; ++i)
        #pragma unroll
        for (int m = 0; m < 4; ++m)
          gates[(r0 + m) * GS + kind * 192 + colG[i]] = ac[i][m] + bg1[i];
    }
    __syncthreads();
    // ===== GRU1: elementwise =====
    #pragma unroll
    for (int q = 0; q < 2; ++q) {
      const int d = d_e + q * 32;
      const float r_ = sigm (gates[gb + d]       + gates[gb + 192 + d]);
      const float z_ = sigm (gates[gb + 64 + d]  + gates[gb + 256 + d]);
      const float n_ = tanh_(gates[gb + 128 + d] + r_ * gates[gb + 320 + d]);
      hg1[q] = (1.0f - z_) * n_ + z_ * hg1[q];
      zG1[r_e * RB1 + 64 + d] = f2bf(hg1[q]);
    }
    __syncthreads();
  }

  // ---------------- FC head ----------------
  hfin[r_e][d_e]      = hg1[0];
  hfin[r_e][d_e + 32] = hg1[1];
  __syncthreads();
  if (tid < 8) {
    float s = fc_b[0];
    #pragma unroll 8
    for (int d = 0; d < 64; ++d) s += hfin[tid][d] * fc_w[d];
    out[rb0 + tid] = s;
  }
}

extern "C" void kernel_launch(void* const* d_in, const int* in_sizes, int n_in,
                              void* d_out, int out_size, void* d_ws, size_t ws_size,
                              hipStream_t stream) {
  const float* x      = (const float*)d_in[0];
  const float* lw_ih0 = (const float*)d_in[1];
  const float* lw_hh0 = (const float*)d_in[2];
  const float* lb_ih0 = (const float*)d_in[3];
  const float* lb_hh0 = (const float*)d_in[4];
  const float* lw_ih1 = (const float*)d_in[5];
  const float* lw_hh1 = (const float*)d_in[6];
  const float* lb_ih1 = (const float*)d_in[7];
  const float* lb_hh1 = (const float*)d_in[8];
  const float* gw_ih0 = (const float*)d_in[9];
  const float* gw_hh0 = (const float*)d_in[10];
  const float* gb_ih0 = (const float*)d_in[11];
  const float* gb_hh0 = (const float*)d_in[12];
  const float* gw_ih1 = (const float*)d_in[13];
  const float* gw_hh1 = (const float*)d_in[14];
  const float* gb_ih1 = (const float*)d_in[15];
  const float* gb_hh1 = (const float*)d_in[16];
  const float* fc_w   = (const float*)d_in[17];
  const float* fc_b   = (const float*)d_in[18];

  rnn_fused<<<dim3(2048 / 8), dim3(512), 0, stream>>>(
      x, lw_ih0, lw_hh0, lb_ih0, lb_hh0, lw_ih1, lw_hh1, lb_ih1, lb_hh1,
      gw_ih0, gw_hh0, gb_ih0, gb_hh0, gw_ih1, gw_hh1, gb_ih1, gb_hh1,
      fc_w, fc_b, (float*)d_out);
}

// Round 3
// 689.571 us; speedup vs baseline: 1.9494x; 1.9494x over previous
//
#include <hip/hip_runtime.h>

// Fused 4-layer RNN (LSTM,LSTM,GRU,GRU, H=64) + FC head. B=2048, T=512.
// 256 blocks x 256 threads (4 waves, 1/SIMD). 8 real batch rows per block,
// placed at A-rows {0,1,4,5,8,9,12,13} so C-layout (row=4*lq+m) gives every
// lane exactly 2 real rows at m={0,1}: elementwise has no mirror waste and
// needs no cross-lane ops. States double-buffered in LDS -> 1 barrier/layer.
// h-part matmuls (prev-step states) issue at step start, off the chain.

#define TT 512
#define SR 72            // state row stride (shorts): 144B, 144/16=9 = 1 mod 8

typedef __attribute__((ext_vector_type(8))) short bfrag;  // 8 bf16
typedef __attribute__((ext_vector_type(4))) float facc;   // 4 f32

#define MFMA(a,b,c) __builtin_amdgcn_mfma_f32_16x16x32_bf16((a),(b),(c),0,0,0)

__device__ __forceinline__ short f2bf(float f){
  union { float f; unsigned u; } v; v.f = f;
  return (short)((v.u + 0x7fffu + ((v.u >> 16) & 1u)) >> 16);  // RNE
}
__device__ __forceinline__ float sigm(float xx){
  return __builtin_amdgcn_rcpf(1.0f + __expf(-xx));
}
__device__ __forceinline__ float tanh_(float xx){
  return 2.0f * __builtin_amdgcn_rcpf(1.0f + __expf(-2.0f * xx)) - 1.0f;
}

__global__ __launch_bounds__(256, 1) void rnn_fused(
    const float* __restrict__ x,
    const float* __restrict__ lw_ih0, const float* __restrict__ lw_hh0,
    const float* __restrict__ lb_ih0, const float* __restrict__ lb_hh0,
    const float* __restrict__ lw_ih1, const float* __restrict__ lw_hh1,
    const float* __restrict__ lb_ih1, const float* __restrict__ lb_hh1,
    const float* __restrict__ gw_ih0, const float* __restrict__ gw_hh0,
    const float* __restrict__ gb_ih0, const float* __restrict__ gb_hh0,
    const float* __restrict__ gw_ih1, const float* __restrict__ gw_hh1,
    const float* __restrict__ gb_ih1, const float* __restrict__ gb_hh1,
    const float* __restrict__ fc_w, const float* __restrict__ fc_b,
    float* __restrict__ out)
{
  // double-buffered bf16 state tiles (A-layout rows; rows 2,3,6,7,... stay 0)
  __shared__ __align__(16) short S0[2][16 * SR];  // h0
  __shared__ __align__(16) short S1[2][16 * SR];  // h1
  __shared__ __align__(16) short S2[2][16 * SR];  // hg0
  __shared__ __align__(16) short S3[2][16 * SR];  // hg1
  __shared__ float xs[8][68];
  __shared__ float hfin[8][68];

  const int tid = threadIdx.x;
  const int w   = tid >> 6;      // wave 0..3 -> h-chunk
  const int l   = tid & 63;
  const int lq  = l >> 4;
  const int lc  = l & 15;
  const int kb  = lq * 8;        // frag k-offset
  const int dl  = w * 16 + lc;   // this wave-lane's h-dim
  const int rb0 = blockIdx.x * 8;

  // ---------------- weights -> VGPRs (48 frags/wave) ----------------
  // B-frag (16x16x32): col = lane&15, k = (lane>>4)*8 + j.
  bfrag wL0[4][2];               // LSTM0 w_hh  (gates i,f,g,o)
  bfrag wx1[4][2], wh1[4][2];    // LSTM1 w_ih / w_hh
  bfrag g0x[3][2], g0h[3][2];    // GRU0 (r,z,n)
  bfrag g1x[3][2], g1h[3][2];    // GRU1
  #pragma unroll
  for (int G = 0; G < 4; ++G) {
    const int col = G * 64 + dl;
    #pragma unroll
    for (int kt = 0; kt < 2; ++kt) {
      bfrag f0, f1, f2;
      #pragma unroll
      for (int j = 0; j < 8; ++j) {
        const int o = col * 64 + kt * 32 + kb + j;
        f0[j] = f2bf(lw_hh0[o]);
        f1[j] = f2bf(lw_ih1[o]);
        f2[j] = f2bf(lw_hh1[o]);
      }
      wL0[G][kt] = f0; wx1[G][kt] = f1; wh1[G][kt] = f2;
    }
  }
  #pragma unroll
  for (int G = 0; G < 3; ++G) {
    const int col = G * 64 + dl;
    #pragma unroll
    for (int kt = 0; kt < 2; ++kt) {
      bfrag f0, f1, f2, f3;
      #pragma unroll
      for (int j = 0; j < 8; ++j) {
        const int o = col * 64 + kt * 32 + kb + j;
        f0[j] = f2bf(gw_ih0[o]);
        f1[j] = f2bf(gw_hh0[o]);
        f2[j] = f2bf(gw_ih1[o]);
        f3[j] = f2bf(gw_hh1[o]);
      }
      g0x[G][kt] = f0; g0h[G][kt] = f1; g1x[G][kt] = f2; g1h[G][kt] = f3;
    }
  }

  // per-lane biases (depend on this lane's gate-col only)
  float bL0[4], bL1[4], wx0[4];
  #pragma unroll
  for (int G = 0; G < 4; ++G) {
    bL0[G] = lb_ih0[G * 64 + dl] + lb_hh0[G * 64 + dl];
    bL1[G] = lb_ih1[G * 64 + dl] + lb_hh1[G * 64 + dl];
    wx0[G] = lw_ih0[G * 64 + dl];
  }
  float brz0[2], brz1[2];
  #pragma unroll
  for (int G = 0; G < 2; ++G) {
    brz0[G] = gb_ih0[G * 64 + dl] + gb_hh0[G * 64 + dl];
    brz1[G] = gb_ih1[G * 64 + dl] + gb_hh1[G * 64 + dl];
  }
  const float bnx0 = gb_ih0[128 + dl], bnh0 = gb_hh0[128 + dl];
  const float bnx1 = gb_ih1[128 + dl], bnh1 = gb_hh1[128 + dl];

  for (int i = tid; i < 16 * SR; i += 256) {
    S0[0][i] = 0; S0[1][i] = 0; S1[0][i] = 0; S1[1][i] = 0;
    S2[0][i] = 0; S2[1][i] = 0; S3[0][i] = 0; S3[1][i] = 0;
  }
  __syncthreads();

  // per-lane recurrent state for batch rows 2lq, 2lq+1 (A-rows 4lq, 4lq+1)
  float c0[2] = {0,0}, c1[2] = {0,0}, h2[2] = {0,0}, h3[2] = {0,0};
  const int wr = (4 * lq) * SR + dl;        // write offset row 4lq
  const float zero4 = 0.0f;
  (void)zero4;

  #pragma unroll 2
  for (int t = 0; t < TT; ++t) {
    const int cur = t & 1, prv = cur ^ 1;
    if ((t & 63) == 0) {  // stage 64 timesteps of x for our 8 rows
      const int row = tid >> 5, tq = (tid & 31) * 2;
      const float2 v = *(const float2*)(x + (rb0 + row) * TT + t + tq);
      xs[row][tq] = v.x; xs[row][tq + 1] = v.y;
      __syncthreads();
    }

    // ======== early: all h-part matmuls from prev-step states ========
    facc aL0[4], aL1h[4], aG0h[3], aG1h[3];
    {
      const short* s = S0[prv];
      const bfrag a0 = *(const bfrag*)(s + lc * SR + kb);
      const bfrag a1 = *(const bfrag*)(s + lc * SR + 32 + kb);
      #pragma unroll
      for (int G = 0; G < 4; ++G) {
        facc a_ = {0,0,0,0};
        a_ = MFMA(a0, wL0[G][0], a_); a_ = MFMA(a1, wL0[G][1], a_);
        aL0[G] = a_;
      }
    }
    {
      const short* s = S1[prv];
      const bfrag a0 = *(const bfrag*)(s + lc * SR + kb);
      const bfrag a1 = *(const bfrag*)(s + lc * SR + 32 + kb);
      #pragma unroll
      for (int G = 0; G < 4; ++G) {
        facc a_ = {0,0,0,0};
        a_ = MFMA(a0, wh1[G][0], a_); a_ = MFMA(a1, wh1[G][1], a_);
        aL1h[G] = a_;
      }
    }
    {
      const short* s = S2[prv];
      const bfrag a0 = *(const bfrag*)(s + lc * SR + kb);
      const bfrag a1 = *(const bfrag*)(s + lc * SR + 32 + kb);
      #pragma unroll
      for (int G = 0; G < 3; ++G) {
        facc a_ = {0,0,0,0};
        a_ = MFMA(a0, g0h[G][0], a_); a_ = MFMA(a1, g0h[G][1], a_);
        aG0h[G] = a_;
      }
    }
    {
      const short* s = S3[prv];
      const bfrag a0 = *(const bfrag*)(s + lc * SR + kb);
      const bfrag a1 = *(const bfrag*)(s + lc * SR + 32 + kb);
      #pragma unroll
      for (int G = 0; G < 3; ++G) {
        facc a_ = {0,0,0,0};
        a_ = MFMA(a0, g1h[G][0], a_); a_ = MFMA(a1, g1h[G][1], a_);
        aG1h[G] = a_;
      }
    }

    // ======== LSTM0 elementwise (matmul == h-part, already done) ========
    {
      const float xv0 = xs[2 * lq][t & 63];
      const float xv1 = xs[2 * lq + 1][t & 63];
      #pragma unroll
      for (int m = 0; m < 2; ++m) {
        const float xv = m ? xv1 : xv0;
        const float i_ = sigm (aL0[0][m] + xv * wx0[0] + bL0[0]);
        const float f_ = sigm (aL0[1][m] + xv * wx0[1] + bL0[1]);
        const float g_ = tanh_(aL0[2][m] + xv * wx0[2] + bL0[2]);
        const float o_ = sigm (aL0[3][m] + xv * wx0[3] + bL0[3]);
        c0[m] = f_ * c0[m] + i_ * g_;
        S0[cur][wr + m * SR] = f2bf(o_ * tanh_(c0[m]));
      }
    }
    __syncthreads();

    // ======== LSTM1: x-part matmul on fresh h0 + elementwise ========
    {
      const short* s = S0[cur];
      const bfrag a0 = *(const bfrag*)(s + lc * SR + kb);
      const bfrag a1 = *(const bfrag*)(s + lc * SR + 32 + kb);
      facc ac[4];
      #pragma unroll
      for (int G = 0; G < 4; ++G) {
        facc a_ = aL1h[G];
        a_ = MFMA(a0, wx1[G][0], a_); a_ = MFMA(a1, wx1[G][1], a_);
        ac[G] = a_;
      }
      #pragma unroll
      for (int m = 0; m < 2; ++m) {
        const float i_ = sigm (ac[0][m] + bL1[0]);
        const float f_ = sigm (ac[1][m] + bL1[1]);
        const float g_ = tanh_(ac[2][m] + bL1[2]);
        const float o_ = sigm (ac[3][m] + bL1[3]);
        c1[m] = f_ * c1[m] + i_ * g_;
        S1[cur][wr + m * SR] = f2bf(o_ * tanh_(c1[m]));
      }
    }
    __syncthreads();

    // ======== GRU0: x-part matmul on fresh h1 + elementwise ========
    {
      const short* s = S1[cur];
      const bfrag a0 = *(const bfrag*)(s + lc * SR + kb);
      const bfrag a1 = *(const bfrag*)(s + lc * SR + 32 + kb);
      facc ax[3];
      #pragma unroll
      for (int G = 0; G < 3; ++G) {
        facc a_ = {0,0,0,0};
        a_ = MFMA(a0, g0x[G][0], a_); a_ = MFMA(a1, g0x[G][1], a_);
        ax[G] = a_;
      }
      #pragma unroll
      for (int m = 0; m < 2; ++m) {
        const float r_ = sigm (ax[0][m] + aG0h[0][m] + brz0[0]);
        const float z_ = sigm (ax[1][m] + aG0h[1][m] + brz0[1]);
        const float n_ = tanh_(ax[2][m] + bnx0 + r_ * (aG0h[2][m] + bnh0));
        h2[m] = (1.0f - z_) * n_ + z_ * h2[m];
        S2[cur][wr + m * SR] = f2bf(h2[m]);
      }
    }
    __syncthreads();

    // ======== GRU1: x-part matmul on fresh hg0 + elementwise ========
    {
      const short* s = S2[cur];
      const bfrag a0 = *(const bfrag*)(s + lc * SR + kb);
      const bfrag a1 = *(const bfrag*)(s + lc * SR + 32 + kb);
      facc ax[3];
      #pragma unroll
      for (int G = 0; G < 3; ++G) {
        facc a_ = {0,0,0,0};
        a_ = MFMA(a0, g1x[G][0], a_); a_ = MFMA(a1, g1x[G][1], a_);
        ax[G] = a_;
      }
      #pragma unroll
      for (int m = 0; m < 2; ++m) {
        const float r_ = sigm (ax[0][m] + aG1h[0][m] + brz1[0]);
        const float z_ = sigm (ax[1][m] + aG1h[1][m] + brz1[1]);
        const float n_ = tanh_(ax[2][m] + bnx1 + r_ * (aG1h[2][m] + bnh1));
        h3[m] = (1.0f - z_) * n_ + z_ * h3[m];
        S3[cur][wr + m * SR] = f2bf(h3[m]);
      }
    }
    __syncthreads();
  }

  // ---------------- FC head ----------------
  hfin[2 * lq][dl]     = h3[0];
  hfin[2 * lq + 1][dl] = h3[1];
  __syncthreads();
  if (tid < 8) {
    float s = fc_b[0];
    #pragma unroll 8
    for (int d = 0; d < 64; ++d) s += hfin[tid][d] * fc_w[d];
    out[rb0 + tid] = s;
  }
}

extern "C" void kernel_launch(void* const* d_in, const int* in_sizes, int n_in,
                              void* d_out, int out_size, void* d_ws, size_t ws_size,
                              hipStream_t stream) {
  const float* x      = (const float*)d_in[0];
  const float* lw_ih0 = (const float*)d_in[1];
  const float* lw_hh0 = (const float*)d_in[2];
  const float* lb_ih0 = (const float*)d_in[3];
  const float* lb_hh0 = (const float*)d_in[4];
  const float* lw_ih1 = (const float*)d_in[5];
  const float* lw_hh1 = (const float*)d_in[6];
  const float* lb_ih1 = (const float*)d_in[7];
  const float* lb_hh1 = (const float*)d_in[8];
  const float* gw_ih0 = (const float*)d_in[9];
  const float* gw_hh0 = (const float*)d_in[10];
  const float* gb_ih0 = (const float*)d_in[11];
  const float* gb_hh0 = (const float*)d_in[12];
  const float* gw_ih1 = (const float*)d_in[13];
  const float* gw_hh1 = (const float*)d_in[14];
  const float* gb_ih1 = (const float*)d_in[15];
  const float* gb_hh1 = (const float*)d_in[16];
  const float* fc_w   = (const float*)d_in[17];
  const float* fc_b   = (const float*)d_in[18];

  rnn_fused<<<dim3(2048 / 8), dim3(256), 0, stream>>>(
      x, lw_ih0, lw_hh0, lb_ih0, lb_hh0, lw_ih1, lw_hh1, lb_ih1, lb_hh1,
      gw_ih0, gw_hh0, gb_ih0, gb_hh0, gw_ih1, gw_hh1, gb_ih1, gb_hh1,
      fc_w, fc_b, (float*)d_out);
}

// Round 4
// 484.486 us; speedup vs baseline: 2.7746x; 1.4233x over previous
//
#include <hip/hip_runtime.h>

// Fused 4-layer RNN (LSTM,LSTM,GRU,GRU, H=64) + FC head. B=2048, T=512.
// Wave-specialized LAYER PIPELINE: 256 blocks x 512 threads (8 waves).
// Tick T: waves{0,1}=LSTM0@t=T, {2,3}=LSTM1@t=T-1, {4,5}=GRU0@t=T-2,
// {6,7}=GRU1@t=T-3. States double-buffered bf16 in LDS; producer writes
// parity T&1, consumers read parity (T-1)&1; ONE barrier per tick.
// Each wave holds only its layer's weights in VGPRs -> no spills.
// Batch rows at A-rows {0,1,4,5,8,9,12,13}: every lane owns rows m={0,1}.

#define TT 512
#define SR 72            // state row stride (shorts)
#define XR 68            // xs/hfin row stride (floats)

typedef __attribute__((ext_vector_type(8))) short bfrag;  // 8 bf16
typedef __attribute__((ext_vector_type(4))) float facc;   // 4 f32

#define MFMA(a,b,c) __builtin_amdgcn_mfma_f32_16x16x32_bf16((a),(b),(c),0,0,0)

__device__ __forceinline__ short f2bf(float f){
  union { float f; unsigned u; } v; v.f = f;
  return (short)((v.u + 0x7fffu + ((v.u >> 16) & 1u)) >> 16);  // RNE
}
__device__ __forceinline__ float sigm(float xx){
  return __builtin_amdgcn_rcpf(1.0f + __expf(-xx));
}
__device__ __forceinline__ float tanh_(float xx){
  return 2.0f * __builtin_amdgcn_rcpf(1.0f + __expf(-2.0f * xx)) - 1.0f;
}

__global__ __launch_bounds__(512, 2) void rnn_fused(
    const float* __restrict__ x,
    const float* __restrict__ lw_ih0, const float* __restrict__ lw_hh0,
    const float* __restrict__ lb_ih0, const float* __restrict__ lb_hh0,
    const float* __restrict__ lw_ih1, const float* __restrict__ lw_hh1,
    const float* __restrict__ lb_ih1, const float* __restrict__ lb_hh1,
    const float* __restrict__ gw_ih0, const float* __restrict__ gw_hh0,
    const float* __restrict__ gb_ih0, const float* __restrict__ gb_hh0,
    const float* __restrict__ gw_ih1, const float* __restrict__ gw_hh1,
    const float* __restrict__ gb_ih1, const float* __restrict__ gb_hh1,
    const float* __restrict__ fc_w, const float* __restrict__ fc_b,
    float* __restrict__ out)
{
  __shared__ __align__(16) short S0[2][16 * SR];  // h0 (LSTM0 out)
  __shared__ __align__(16) short S1[2][16 * SR];  // h1 (LSTM1 out)
  __shared__ __align__(16) short S2[2][16 * SR];  // h2 (GRU0 out)
  __shared__ __align__(16) short S3[2][16 * SR];  // h3 (GRU1 out)
  __shared__ float xs[8][XR];
  __shared__ float hfin[8][XR];

  const int tid = threadIdx.x;
  const int w   = tid >> 6;        // wave 0..7
  const int layer = w >> 1;        // 0..3
  const int loc   = w & 1;         // 0/1: h-dim half [loc*32, loc*32+32)
  const int l   = tid & 63;
  const int lq  = l >> 4;
  const int lc  = l & 15;
  const int kb  = lq * 8;
  const int rb0 = blockIdx.x * 8;
  const int wrbase = (4 * lq) * SR + loc * 32 + lc;  // + m*SR + q*16

  for (int i = tid; i < 16 * SR; i += 512) {
    S0[0][i] = 0; S0[1][i] = 0; S1[0][i] = 0; S1[1][i] = 0;
    S2[0][i] = 0; S2[1][i] = 0; S3[0][i] = 0; S3[1][i] = 0;
  }
  __syncthreads();

  // staged x: every 64 ticks, each wave loads its batch row's next 64 steps
  #define STAGE_X()                                         \
    if ((T & 63) == 0 && T < TT) {                          \
      xs[w][l] = x[(rb0 + w) * TT + T + l];                 \
      __syncthreads();                                      \
    }

  if (layer == 0) {
    // ================= LSTM0: t = T, K=64 (h0 only; x is scalar FMA) ========
    bfrag wf[4][2][2];           // [gate][chunk q][ktile]
    float wxs[4][2], bs[4][2];
    #pragma unroll
    for (int G = 0; G < 4; ++G)
      #pragma unroll
      for (int q = 0; q < 2; ++q) {
        const int col = G * 64 + loc * 32 + q * 16 + lc;
        #pragma unroll
        for (int kt = 0; kt < 2; ++kt) {
          bfrag f;
          #pragma unroll
          for (int j = 0; j < 8; ++j) f[j] = f2bf(lw_hh0[col * 64 + kt * 32 + kb + j]);
          wf[G][q][kt] = f;
        }
        wxs[G][q] = lw_ih0[col];
        bs[G][q]  = lb_ih0[col] + lb_hh0[col];
      }
    float c0[2][2] = {{0,0},{0,0}};
    #pragma unroll 2
    for (int T = 0; T < TT + 3; ++T) {
      const int cur = T & 1, prv = cur ^ 1;
      STAGE_X();
      if (T < TT) {
        const short* s = S0[prv];
        const bfrag a0 = *(const bfrag*)(s + lc * SR + kb);
        const bfrag a1 = *(const bfrag*)(s + lc * SR + 32 + kb);
        facc acc[4][2];
        #pragma unroll
        for (int G = 0; G < 4; ++G)
          #pragma unroll
          for (int q = 0; q < 2; ++q) {
            facc z = {0,0,0,0};
            z = MFMA(a0, wf[G][q][0], z);
            z = MFMA(a1, wf[G][q][1], z);
            acc[G][q] = z;
          }
        #pragma unroll
        for (int m = 0; m < 2; ++m) {
          const float xv = xs[2 * lq + m][T & 63];
          #pragma unroll
          for (int q = 0; q < 2; ++q) {
            const float i_ = sigm (acc[0][q][m] + xv * wxs[0][q] + bs[0][q]);
            const float f_ = sigm (acc[1][q][m] + xv * wxs[1][q] + bs[1][q]);
            const float g_ = tanh_(acc[2][q][m] + xv * wxs[2][q] + bs[2][q]);
            const float o_ = sigm (acc[3][q][m] + xv * wxs[3][q] + bs[3][q]);
            c0[q][m] = f_ * c0[q][m] + i_ * g_;
            S0[cur][wrbase + m * SR + q * 16] = f2bf(o_ * tanh_(c0[q][m]));
          }
        }
      }
      __syncthreads();
    }
  } else if (layer == 1) {
    // ================= LSTM1: t = T-1, K=128 ([h0_t | h1_{t-1}]) ============
    bfrag wxf[4][2][2], whf[4][2][2];
    float bs[4][2];
    #pragma unroll
    for (int G = 0; G < 4; ++G)
      #pragma unroll
      for (int q = 0; q < 2; ++q) {
        const int col = G * 64 + loc * 32 + q * 16 + lc;
        #pragma unroll
        for (int kt = 0; kt < 2; ++kt) {
          bfrag f0, f1;
          #pragma unroll
          for (int j = 0; j < 8; ++j) {
            const int o = col * 64 + kt * 32 + kb + j;
            f0[j] = f2bf(lw_ih1[o]);
            f1[j] = f2bf(lw_hh1[o]);
          }
          wxf[G][q][kt] = f0; whf[G][q][kt] = f1;
        }
        bs[G][q] = lb_ih1[col] + lb_hh1[col];
      }
    float c1[2][2] = {{0,0},{0,0}};
    #pragma unroll 2
    for (int T = 0; T < TT + 3; ++T) {
      const int cur = T & 1, prv = cur ^ 1;
      STAGE_X();
      if (T >= 1 && T <= TT) {
        const short* sx = S0[prv];
        const short* sh = S1[prv];
        const bfrag ax0 = *(const bfrag*)(sx + lc * SR + kb);
        const bfrag ax1 = *(const bfrag*)(sx + lc * SR + 32 + kb);
        const bfrag ah0 = *(const bfrag*)(sh + lc * SR + kb);
        const bfrag ah1 = *(const bfrag*)(sh + lc * SR + 32 + kb);
        facc acc[4][2];
        #pragma unroll
        for (int G = 0; G < 4; ++G)
          #pragma unroll
          for (int q = 0; q < 2; ++q) {
            facc z = {0,0,0,0};
            z = MFMA(ax0, wxf[G][q][0], z);
            z = MFMA(ax1, wxf[G][q][1], z);
            z = MFMA(ah0, whf[G][q][0], z);
            z = MFMA(ah1, whf[G][q][1], z);
            acc[G][q] = z;
          }
        #pragma unroll
        for (int m = 0; m < 2; ++m)
          #pragma unroll
          for (int q = 0; q < 2; ++q) {
            const float i_ = sigm (acc[0][q][m] + bs[0][q]);
            const float f_ = sigm (acc[1][q][m] + bs[1][q]);
            const float g_ = tanh_(acc[2][q][m] + bs[2][q]);
            const float o_ = sigm (acc[3][q][m] + bs[3][q]);
            c1[q][m] = f_ * c1[q][m] + i_ * g_;
            S1[cur][wrbase + m * SR + q * 16] = f2bf(o_ * tanh_(c1[q][m]));
          }
      }
      __syncthreads();
    }
  } else if (layer == 2) {
    // ================= GRU0: t = T-2 (x-part = h1_t, h-part = h2_{t-1}) =====
    bfrag gx[3][2][2], gh[3][2][2];
    float brz[2][2], bnx[2], bnh[2];
    #pragma unroll
    for (int G = 0; G < 3; ++G)
      #pragma unroll
      for (int q = 0; q < 2; ++q) {
        const int col = G * 64 + loc * 32 + q * 16 + lc;
        #pragma unroll
        for (int kt = 0; kt < 2; ++kt) {
          bfrag f0, f1;
          #pragma unroll
          for (int j = 0; j < 8; ++j) {
            const int o = col * 64 + kt * 32 + kb + j;
            f0[j] = f2bf(gw_ih0[o]);
            f1[j] = f2bf(gw_hh0[o]);
          }
          gx[G][q][kt] = f0; gh[G][q][kt] = f1;
        }
        if (G < 2) brz[G][q] = gb_ih0[col] + gb_hh0[col];
        else { bnx[q] = gb_ih0[col]; bnh[q] = gb_hh0[col]; }
      }
    float h2[2][2] = {{0,0},{0,0}};
    #pragma unroll 2
    for (int T = 0; T < TT + 3; ++T) {
      const int cur = T & 1, prv = cur ^ 1;
      STAGE_X();
      if (T >= 2 && T <= TT + 1) {
        const short* sx = S1[prv];
        const short* sh = S2[prv];
        const bfrag ax0 = *(const bfrag*)(sx + lc * SR + kb);
        const bfrag ax1 = *(const bfrag*)(sx + lc * SR + 32 + kb);
        const bfrag ah0 = *(const bfrag*)(sh + lc * SR + kb);
        const bfrag ah1 = *(const bfrag*)(sh + lc * SR + 32 + kb);
        facc ax[3][2], ah[3][2];
        #pragma unroll
        for (int G = 0; G < 3; ++G)
          #pragma unroll
          for (int q = 0; q < 2; ++q) {
            facc z = {0,0,0,0};
            z = MFMA(ax0, gx[G][q][0], z);
            z = MFMA(ax1, gx[G][q][1], z);
            ax[G][q] = z;
            facc y = {0,0,0,0};
            y = MFMA(ah0, gh[G][q][0], y);
            y = MFMA(ah1, gh[G][q][1], y);
            ah[G][q] = y;
          }
        #pragma unroll
        for (int m = 0; m < 2; ++m)
          #pragma unroll
          for (int q = 0; q < 2; ++q) {
            const float r_ = sigm (ax[0][q][m] + ah[0][q][m] + brz[0][q]);
            const float z_ = sigm (ax[1][q][m] + ah[1][q][m] + brz[1][q]);
            const float n_ = tanh_(ax[2][q][m] + bnx[q] + r_ * (ah[2][q][m] + bnh[q]));
            h2[q][m] = (1.0f - z_) * n_ + z_ * h2[q][m];
            S2[cur][wrbase + m * SR + q * 16] = f2bf(h2[q][m]);
          }
      }
      __syncthreads();
    }
  } else {
    // ================= GRU1: t = T-3 (x-part = h2_t, h-part = h3_{t-1}) =====
    bfrag gx[3][2][2], gh[3][2][2];
    float brz[2][2], bnx[2], bnh[2];
    #pragma unroll
    for (int G = 0; G < 3; ++G)
      #pragma unroll
      for (int q = 0; q < 2; ++q) {
        const int col = G * 64 + loc * 32 + q * 16 + lc;
        #pragma unroll
        for (int kt = 0; kt < 2; ++kt) {
          bfrag f0, f1;
          #pragma unroll
          for (int j = 0; j < 8; ++j) {
            const int o = col * 64 + kt * 32 + kb + j;
            f0[j] = f2bf(gw_ih1[o]);
            f1[j] = f2bf(gw_hh1[o]);
          }
          gx[G][q][kt] = f0; gh[G][q][kt] = f1;
        }
        if (G < 2) brz[G][q] = gb_ih1[col] + gb_hh1[col];
        else { bnx[q] = gb_ih1[col]; bnh[q] = gb_hh1[col]; }
      }
    float h3[2][2] = {{0,0},{0,0}};
    #pragma unroll 2
    for (int T = 0; T < TT + 3; ++T) {
      const int cur = T & 1, prv = cur ^ 1;
      STAGE_X();
      if (T >= 3) {
        const short* sx = S2[prv];
        const short* sh = S3[prv];
        const bfrag ax0 = *(const bfrag*)(sx + lc * SR + kb);
        const bfrag ax1 = *(const bfrag*)(sx + lc * SR + 32 + kb);
        const bfrag ah0 = *(const bfrag*)(sh + lc * SR + kb);
        const bfrag ah1 = *(const bfrag*)(sh + lc * SR + 32 + kb);
        facc ax[3][2], ah[3][2];
        #pragma unroll
        for (int G = 0; G < 3; ++G)
          #pragma unroll
          for (int q = 0; q < 2; ++q) {
            facc z = {0,0,0,0};
            z = MFMA(ax0, gx[G][q][0], z);
            z = MFMA(ax1, gx[G][q][1], z);
            ax[G][q] = z;
            facc y = {0,0,0,0};
            y = MFMA(ah0, gh[G][q][0], y);
            y = MFMA(ah1, gh[G][q][1], y);
            ah[G][q] = y;
          }
        #pragma unroll
        for (int m = 0; m < 2; ++m)
          #pragma unroll
          for (int q = 0; q < 2; ++q) {
            const float r_ = sigm (ax[0][q][m] + ah[0][q][m] + brz[0][q]);
            const float z_ = sigm (ax[1][q][m] + ah[1][q][m] + brz[1][q]);
            const float n_ = tanh_(ax[2][q][m] + bnx[q] + r_ * (ah[2][q][m] + bnh[q]));
            h3[q][m] = (1.0f - z_) * n_ + z_ * h3[q][m];
            S3[cur][wrbase + m * SR + q * 16] = f2bf(h3[q][m]);
          }
      }
      __syncthreads();
    }
    // final hidden state -> hfin (batch row = 2lq+m)
    #pragma unroll
    for (int m = 0; m < 2; ++m)
      #pragma unroll
      for (int q = 0; q < 2; ++q)
        hfin[2 * lq + m][loc * 32 + q * 16 + lc] = h3[q][m];
  }

  __syncthreads();
  if (tid < 8) {
    float s = fc_b[0];
    #pragma unroll 8
    for (int d = 0; d < 64; ++d) s += hfin[tid][d] * fc_w[d];
    out[rb0 + tid] = s;
  }
}

extern "C" void kernel_launch(void* const* d_in, const int* in_sizes, int n_in,
                              void* d_out, int out_size, void* d_ws, size_t ws_size,
                              hipStream_t stream) {
  const float* x      = (const float*)d_in[0];
  const float* lw_ih0 = (const float*)d_in[1];
  const float* lw_hh0 = (const float*)d_in[2];
  const float* lb_ih0 = (const float*)d_in[3];
  const float* lb_hh0 = (const float*)d_in[4];
  const float* lw_ih1 = (const float*)d_in[5];
  const float* lw_hh1 = (const float*)d_in[6];
  const float* lb_ih1 = (const float*)d_in[7];
  const float* lb_hh1 = (const float*)d_in[8];
  const float* gw_ih0 = (const float*)d_in[9];
  const float* gw_hh0 = (const float*)d_in[10];
  const float* gb_ih0 = (const float*)d_in[11];
  const float* gb_hh0 = (const float*)d_in[12];
  const float* gw_ih1 = (const float*)d_in[13];
  const float* gw_hh1 = (const float*)d_in[14];
  const float* gb_ih1 = (const float*)d_in[15];
  const float* gb_hh1 = (const float*)d_in[16];
  const float* fc_w   = (const float*)d_in[17];
  const float* fc_b   = (const float*)d_in[18];

  rnn_fused<<<dim3(2048 / 8), dim3(512), 0, stream>>>(
      x, lw_ih0, lw_hh0, lb_ih0, lb_hh0, lw_ih1, lw_hh1, lb_ih1, lb_hh1,
      gw_ih0, gw_hh0, gb_ih0, gb_hh0, gw_ih1, gw_hh1, gb_ih1, gb_hh1,
      fc_w, fc_b, (float*)d_out);
}